// Round 6
// baseline (2437.134 us; speedup 1.0000x reference)
//
#include <hip/hip_runtime.h>

#define NPTS 256
#define NBATCH 64
#define BIGF 1e30f

__device__ __forceinline__ float rlane(float v, int l) {
    return __uint_as_float((unsigned int)__builtin_amdgcn_readlane((int)__float_as_uint(v), l));
}
__device__ __forceinline__ int rlanei(int v, int l) {
    return __builtin_amdgcn_readlane(v, l);
}
__device__ __forceinline__ float rawsqrt(float x) {
    return __builtin_amdgcn_sqrtf(x);
}

// Uniform-slot select (slot wave-uniform); cold paths only.
#define SEL4(a, s) ((s) == 0 ? a[0] : (s) == 1 ? a[1] : (s) == 2 ? a[2] : a[3])

#define DPP_UMIN(v, ctrl) \
    (min)((v), (unsigned int)__builtin_amdgcn_update_dpp( \
        (int)(v), (int)(v), (ctrl), 0xf, 0xf, false))

// Full-wave u32 min; uniform result via lane-63 readlane.
__device__ __forceinline__ unsigned int wave_umin_bcast(unsigned int v) {
    v = DPP_UMIN(v, 0x111);   // row_shr:1
    v = DPP_UMIN(v, 0x112);   // row_shr:2
    v = DPP_UMIN(v, 0x114);   // row_shr:4
    v = DPP_UMIN(v, 0x118);   // row_shr:8
    v = DPP_UMIN(v, 0x142);   // row_bcast:15
    v = DPP_UMIN(v, 0x143);   // row_bcast:31
    return (unsigned int)rlanei((int)v, 63);
}

// Full-wave (min, 2nd-min) pair over u32 keys, via row_ror (all lanes valid -> no
// self-combine pair corruption) + row_bcast (corrupted lanes never feed lane 63).
struct PairU { unsigned int m1, m2; };
__device__ __forceinline__ PairU wave_pairmin_bcast(unsigned int m1, unsigned int m2) {
#define PSTEP(ctrl) { \
    unsigned int o1 = (unsigned int)__builtin_amdgcn_update_dpp((int)m1, (int)m1, (ctrl), 0xf, 0xf, false); \
    unsigned int o2 = (unsigned int)__builtin_amdgcn_update_dpp((int)m2, (int)m2, (ctrl), 0xf, 0xf, false); \
    unsigned int hi = (max)(m1, o1); \
    m1 = (min)(m1, o1); \
    m2 = (min)(hi, (min)(m2, o2)); }
    PSTEP(0x121)  // row_ror:1
    PSTEP(0x122)  // row_ror:2
    PSTEP(0x124)  // row_ror:4
    PSTEP(0x128)  // row_ror:8
    PSTEP(0x142)  // row_bcast:15
    PSTEP(0x143)  // row_bcast:31
#undef PSTEP
    PairU r;
    r.m1 = (unsigned int)rlanei((int)m1, 63);
    r.m2 = (unsigned int)rlanei((int)m2, 63);
    return r;
}

__global__ void zero_out_kernel(float* out, int n) {
    int i = blockIdx.x * blockDim.x + threadIdx.x;
    if (i < n) out[i] = 0.0f;
}

// One wave per batch; lane owns columns/rows {lane, 64+lane, 128+lane, 192+lane}.
// JV: column reduction -> greedy claim -> augmenting row reduction (single
// pair-DPP chain per step) -> delta-accumulated Dijkstra for leftovers.
// Register-resident; cross-lane via readlane/DPP. No LDS, no barriers.
__launch_bounds__(64, 1)
__global__ void hungarian_wave(const float* __restrict__ pred,
                               const float* __restrict__ target,
                               float* __restrict__ out) {
    const int b    = blockIdx.x;
    const int lane = threadIdx.x;

    const float* pb = pred   + (size_t)b * NPTS * 3;
    const float* tb = target + (size_t)b * NPTS * 3;

    float prx[4], pry[4], prz[4];      // pred (row) points, row = c*64+lane
    float tx[4], ty[4], tz[4];         // target (col) points, col = c*64+lane
    float vv[4], upc[4], Mv[4];
    float rxc[4], ryc[4], rzc[4];      // matched-row coords, column-attached
    int   pc[4]  = {-1, -1, -1, -1};   // matched row per column (-1 = free)
    int   way[4];
    unsigned int colu[4];              // this lane's column ids

#pragma unroll
    for (int c = 0; c < 4; ++c) {
        int idx = c * 64 + lane;
        prx[c] = pb[idx * 3 + 0]; pry[c] = pb[idx * 3 + 1]; prz[c] = pb[idx * 3 + 2];
        tx[c]  = tb[idx * 3 + 0]; ty[c]  = tb[idx * 3 + 1]; tz[c]  = tb[idx * 3 + 2];
        upc[c] = 0.f; rxc[c] = 0.f; ryc[c] = 0.f; rzc[c] = 0.f;
        colu[c] = (unsigned int)idx;
    }

    // ---- Phase 1a: column reduction. vv[c] = min_r d(r, col), colrow = argmin ----
    float colmin[4] = {BIGF, BIGF, BIGF, BIGF};
    int   colrow[4] = {0, 0, 0, 0};
#pragma unroll
    for (int rs = 0; rs < 4; ++rs) {
        for (int rl = 0; rl < 64; ++rl) {
            float bx = rlane(prx[rs], rl), by = rlane(pry[rs], rl), bz = rlane(prz[rs], rl);
            int r = rs * 64 + rl;
#pragma unroll
            for (int c = 0; c < 4; ++c) {
                float dx = bx - tx[c], dy = by - ty[c], dz = bz - tz[c];
                float d = rawsqrt(dx * dx + dy * dy + dz * dz);
                if (d < colmin[c]) { colmin[c] = d; colrow[c] = r; }
            }
        }
    }
#pragma unroll
    for (int c = 0; c < 4; ++c) vv[c] = colmin[c];

    // ---- Phase 1b: greedy claim — column (ascending) claims its argmin row if free ----
    unsigned long long frm[4];         // free-row masks (wave-uniform values)
    frm[0] = frm[1] = frm[2] = frm[3] = ~0ull;
#pragma unroll
    for (int cs = 0; cs < 4; ++cs) {
        for (int l = 0; l < 64; ++l) {
            int r = rlanei(colrow[cs], l);
            int rs = r >> 6, rl2 = r & 63;
            unsigned long long bit = 1ull << rl2;
            bool free_row = (SEL4(frm, rs) & bit) != 0ull;
            if (free_row) {
#pragma unroll
                for (int s = 0; s < 4; ++s)
                    if (s == rs) frm[s] &= ~bit;
                float bx, by, bz;
                switch (rs) {
                    case 0:  bx = rlane(prx[0], rl2); by = rlane(pry[0], rl2); bz = rlane(prz[0], rl2); break;
                    case 1:  bx = rlane(prx[1], rl2); by = rlane(pry[1], rl2); bz = rlane(prz[1], rl2); break;
                    case 2:  bx = rlane(prx[2], rl2); by = rlane(pry[2], rl2); bz = rlane(prz[2], rl2); break;
                    default: bx = rlane(prx[3], rl2); by = rlane(pry[3], rl2); bz = rlane(prz[3], rl2); break;
                }
                if (lane == l) {
                    pc[cs] = r; upc[cs] = 0.f;
                    rxc[cs] = bx; ryc[cs] = by; rzc[cs] = bz;
                }
            }
        }
    }

    // ---- Phase 1c: augmenting row reduction (ARR), one pair-DPP chain per step ----
    // Free row i: r[j] = d(i,j) - v[j] >= 0. mu1 = min (argmin j1), mu2 = 2nd min.
    // Claim j1: v[j1] -= (mu2-mu1), u[i] = mu2; displaced row re-enters pool.
    // Truncated (24-bit) keys preserve dual feasibility exactly (mu <= true mins).
    unsigned long long dfm[4] = {0ull, 0ull, 0ull, 0ull};
    {
        int budget = 1024;
        while (budget-- > 0) {
            int is;
            if      (frm[0]) is = 0;
            else if (frm[1]) is = 1;
            else if (frm[2]) is = 2;
            else if (frm[3]) is = 3;
            else break;
            unsigned long long mm = SEL4(frm, is);
            const int il = (int)__builtin_ctzll(mm);
            mm &= mm - 1;
            switch (is) { case 0: frm[0] = mm; break; case 1: frm[1] = mm; break;
                          case 2: frm[2] = mm; break; default: frm[3] = mm; break; }
            const int i = is * 64 + il;

            float bx, by, bz;
            switch (is) {
                case 0:  bx = rlane(prx[0], il); by = rlane(pry[0], il); bz = rlane(prz[0], il); break;
                case 1:  bx = rlane(prx[1], il); by = rlane(pry[1], il); bz = rlane(prz[1], il); break;
                case 2:  bx = rlane(prx[2], il); by = rlane(pry[2], il); bz = rlane(prz[2], il); break;
                default: bx = rlane(prx[3], il); by = rlane(pry[3], il); bz = rlane(prz[3], il); break;
            }

            unsigned int k[4];
#pragma unroll
            for (int c = 0; c < 4; ++c) {
                float dx = bx - tx[c], dy = by - ty[c], dz = bz - tz[c];
                float d = rawsqrt(dx * dx + dy * dy + dz * dz);
                float r = d - vv[c];                       // >= 0 by feasibility
                k[c] = (__float_as_uint(r) & 0xFFFFFF00u) | colu[c];
            }
            // local (min, 2nd-min) fold over 4 distinct keys
            unsigned int a1 = (min)(k[0], k[1]), a2 = (max)(k[0], k[1]);
            unsigned int b1 = (min)(k[2], k[3]), b2 = (max)(k[2], k[3]);
            unsigned int lm1 = (min)(a1, b1);
            unsigned int lm2 = (min)((max)(a1, b1), (min)(a2, b2));

            const PairU p = wave_pairmin_bcast(lm1, lm2);
            const int   j1  = (int)(p.m1 & 0xFFu);
            const float mu1 = __uint_as_float(p.m1 & 0xFFFFFF00u);
            const float mu2 = __uint_as_float(p.m2 & 0xFFFFFF00u);
            const float amt = mu2 - mu1;                   // >= 0
            const int osl = j1 >> 6, oln = j1 & 63;

            int pj1;
            switch (osl) {
                case 0:  pj1 = rlanei(pc[0], oln); break;
                case 1:  pj1 = rlanei(pc[1], oln); break;
                case 2:  pj1 = rlanei(pc[2], oln); break;
                default: pj1 = rlanei(pc[3], oln); break;
            }
            if (pj1 >= 0 && !(amt > 0.f)) {                // zero-progress steal: defer
                switch (is) { case 0: dfm[0] |= 1ull << il; break; case 1: dfm[1] |= 1ull << il; break;
                              case 2: dfm[2] |= 1ull << il; break; default: dfm[3] |= 1ull << il; break; }
                continue;
            }
            // Claim column j1 for row i (applies also when j1 free; v drop keeps CS)
#pragma unroll
            for (int c = 0; c < 4; ++c)
                if (c == osl && lane == oln) {
                    vv[c] -= amt; pc[c] = i; upc[c] = mu2;
                    rxc[c] = bx; ryc[c] = by; rzc[c] = bz;
                }
            if (pj1 >= 0) {                                // displaced row re-enters
                const int ps = pj1 >> 6;
                const unsigned long long pbit = 1ull << (pj1 & 63);
                switch (ps) { case 0: frm[0] |= pbit; break; case 1: frm[1] |= pbit; break;
                              case 2: frm[2] |= pbit; break; default: frm[3] |= pbit; break; }
            }
        }
    }

    // ---- Phase 2: Dijkstra shortest-path for remaining free rows ----
    float D = 0.f;
#pragma unroll
    for (int is = 0; is < 4; ++is) {
        unsigned long long m = frm[is] | dfm[is];
        while (m) {
            const int il = (int)__builtin_ctzll(m);
            m &= (m - 1);
            const int i = is * 64 + il;

            float rootx, rooty, rootz;
            switch (is) {
                case 0:  rootx = rlane(prx[0], il); rooty = rlane(pry[0], il); rootz = rlane(prz[0], il); break;
                case 1:  rootx = rlane(prx[1], il); rooty = rlane(pry[1], il); rootz = rlane(prz[1], il); break;
                case 2:  rootx = rlane(prx[2], il); rooty = rlane(pry[2], il); rootz = rlane(prz[2], il); break;
                default: rootx = rlane(prx[3], il); rooty = rlane(pry[3], il); rootz = rlane(prz[3], il); break;
            }

#pragma unroll
            for (int c = 0; c < 4; ++c) Mv[c] = BIGF;
            int usedm = 0;

            float bx = rootx, by = rooty, bz = rootz;
            float ukey = 0.f;      // u[i0] - D_at_entry
            int j0 = -1;
            int jfin = 0;

            while (true) {
                float t[4];
#pragma unroll
                for (int c = 0; c < 4; ++c) t[c] = vv[c] + ukey;

                unsigned int kmin = 0xFFFFFFFFu;
#pragma unroll
                for (int c = 0; c < 4; ++c) {
                    float dx = bx - tx[c], dy = by - ty[c], dz = bz - tz[c];
                    float d = rawsqrt(dx * dx + dy * dy + dz * dz);
                    float cand = d - t[c];
                    const bool fr = !((usedm >> c) & 1);
                    if (fr && cand < Mv[c]) { Mv[c] = cand; way[c] = j0; }
                    unsigned int key = fr ? ((__float_as_uint(Mv[c]) & 0xFFFFFF00u) | colu[c])
                                          : 0xFFFFFFFFu;
                    kmin = (min)(kmin, key);
                }
                const unsigned int kk = wave_umin_bcast(kmin);
                const int   j1   = (int)(kk & 0xFFu);
                const float gmin = __uint_as_float(kk & 0xFFFFFF00u);
                const int osl = j1 >> 6, oln = j1 & 63;

                int pj; float uj, nbx, nby, nbz;
                switch (osl) {
                    case 0:  pj = rlanei(pc[0], oln); uj = rlane(upc[0], oln); nbx = rlane(rxc[0], oln); nby = rlane(ryc[0], oln); nbz = rlane(rzc[0], oln); break;
                    case 1:  pj = rlanei(pc[1], oln); uj = rlane(upc[1], oln); nbx = rlane(rxc[1], oln); nby = rlane(ryc[1], oln); nbz = rlane(rzc[1], oln); break;
                    case 2:  pj = rlanei(pc[2], oln); uj = rlane(upc[2], oln); nbx = rlane(rxc[2], oln); nby = rlane(ryc[2], oln); nbz = rlane(rzc[2], oln); break;
                    default: pj = rlanei(pc[3], oln); uj = rlane(upc[3], oln); nbx = rlane(rxc[3], oln); nby = rlane(ryc[3], oln); nbz = rlane(rzc[3], oln); break;
                }
                if (pj < 0) { jfin = j1; D = gmin; break; }

#pragma unroll
                for (int c = 0; c < 4; ++c)
                    if (c == osl && lane == oln) {
                        usedm |= (1 << c);
                        vv[c] += gmin;
                        upc[c] -= gmin;
                    }

                bx = nbx; by = nby; bz = nbz;
                ukey = uj - gmin;
                j0 = j1;
            }

#pragma unroll
            for (int c = 0; c < 4; ++c)
                if ((usedm >> c) & 1) { vv[c] -= D; upc[c] += D; }

            int jc = jfin;
            while (true) {
                const int osl = jc >> 6, oln = jc & 63;
                int jw;
                switch (osl) {
                    case 0:  jw = rlanei(way[0], oln); break;
                    case 1:  jw = rlanei(way[1], oln); break;
                    case 2:  jw = rlanei(way[2], oln); break;
                    default: jw = rlanei(way[3], oln); break;
                }
                int np_; float nup, nrx, nry, nrz;
                if (jw < 0) {
                    np_ = i; nup = D; nrx = rootx; nry = rooty; nrz = rootz;
                } else {
                    const int wsl = jw >> 6, wln = jw & 63;
                    switch (wsl) {
                        case 0:  np_ = rlanei(pc[0], wln); nup = rlane(upc[0], wln); nrx = rlane(rxc[0], wln); nry = rlane(ryc[0], wln); nrz = rlane(rzc[0], wln); break;
                        case 1:  np_ = rlanei(pc[1], wln); nup = rlane(upc[1], wln); nrx = rlane(rxc[1], wln); nry = rlane(ryc[1], wln); nrz = rlane(rzc[1], wln); break;
                        case 2:  np_ = rlanei(pc[2], wln); nup = rlane(upc[2], wln); nrx = rlane(rxc[2], wln); nry = rlane(ryc[2], wln); nrz = rlane(rzc[2], wln); break;
                        default: np_ = rlanei(pc[3], wln); nup = rlane(upc[3], wln); nrx = rlane(rxc[3], wln); nry = rlane(ryc[3], wln); nrz = rlane(rzc[3], wln); break;
                    }
                }
#pragma unroll
                for (int c = 0; c < 4; ++c)
                    if (c == osl && lane == oln) {
                        pc[c] = np_; upc[c] = nup;
                        rxc[c] = nrx; ryc[c] = nry; rzc[c] = nrz;
                    }
                if (jw < 0) break;
                jc = jw;
            }
        }
    }

    // ---- Matched cost (coords column-attached; IEEE sqrt for final accuracy) ----
    float s = 0.f;
#pragma unroll
    for (int c = 0; c < 4; ++c) {
        float dx = rxc[c] - tx[c], dy = ryc[c] - ty[c], dz = rzc[c] - tz[c];
        s += sqrtf(dx * dx + dy * dy + dz * dz);
    }
#pragma unroll
    for (int off = 1; off < 64; off <<= 1) s += __shfl_xor(s, off, 64);
    if (lane == 0) atomicAdd(out, s / (float)NBATCH);
}

extern "C" void kernel_launch(void* const* d_in, const int* in_sizes, int n_in,
                              void* d_out, int out_size, void* d_ws, size_t ws_size,
                              hipStream_t stream) {
    const float* pred   = (const float*)d_in[0];
    const float* target = (const float*)d_in[1];
    float* out = (float*)d_out;

    zero_out_kernel<<<1, 64, 0, stream>>>(out, out_size);
    hungarian_wave<<<NBATCH, 64, 0, stream>>>(pred, target, out);
}

// Round 7
// 2123.638 us; speedup vs baseline: 1.1476x; 1.1476x over previous
//
#include <hip/hip_runtime.h>

#define NPTS 256
#define NBATCH 64
#define BIGF 1e30f

__device__ __forceinline__ float rlane(float v, int l) {
    return __uint_as_float((unsigned int)__builtin_amdgcn_readlane((int)__float_as_uint(v), l));
}
__device__ __forceinline__ int rlanei(int v, int l) {
    return __builtin_amdgcn_readlane(v, l);
}
__device__ __forceinline__ float rawsqrt(float x) {
    return __builtin_amdgcn_sqrtf(x);
}

// Uniform-slot select (slot wave-uniform); cold paths only.
#define SEL4(a, s) ((s) == 0 ? a[0] : (s) == 1 ? a[1] : (s) == 2 ? a[2] : a[3])

// Full-wave (min, 2nd-min) pair over u32 keys. row_ror steps keep combined
// element-sets disjoint (contiguous windows), so the pair algebra is exact;
// row_bcast steps combine disjoint row-sets on the lanes that feed lane 63.
// Validated end-to-end in R6 (absmax 0.0).
struct PairU { unsigned int m1, m2; };
__device__ __forceinline__ PairU wave_pairmin_bcast(unsigned int m1, unsigned int m2) {
#define PSTEP(ctrl) { \
    unsigned int o1 = (unsigned int)__builtin_amdgcn_update_dpp((int)m1, (int)m1, (ctrl), 0xf, 0xf, false); \
    unsigned int o2 = (unsigned int)__builtin_amdgcn_update_dpp((int)m2, (int)m2, (ctrl), 0xf, 0xf, false); \
    unsigned int hi = (max)(m1, o1); \
    m1 = (min)(m1, o1); \
    m2 = (min)(hi, (min)(m2, o2)); }
    PSTEP(0x121)  // row_ror:1
    PSTEP(0x122)  // row_ror:2
    PSTEP(0x124)  // row_ror:4
    PSTEP(0x128)  // row_ror:8
    PSTEP(0x142)  // row_bcast:15
    PSTEP(0x143)  // row_bcast:31
#undef PSTEP
    PairU r;
    r.m1 = (unsigned int)rlanei((int)m1, 63);
    r.m2 = (unsigned int)rlanei((int)m2, 63);
    return r;
}

__global__ void zero_out_kernel(float* out, int n) {
    int i = blockIdx.x * blockDim.x + threadIdx.x;
    if (i < n) out[i] = 0.0f;
}

// One wave per batch; lane owns columns/rows {lane, 64+lane, 128+lane, 192+lane}.
// JV: column reduction -> greedy claim -> delta-accumulated Dijkstra searches
// with spare-minimum skip (settle-2). No ARR (R6: ARR weakens v -> longer
// searches). Register-resident; cross-lane via readlane/DPP. No LDS/barriers.
__launch_bounds__(64, 1)
__global__ void hungarian_wave(const float* __restrict__ pred,
                               const float* __restrict__ target,
                               float* __restrict__ out) {
    const int b    = blockIdx.x;
    const int lane = threadIdx.x;

    const float* pb = pred   + (size_t)b * NPTS * 3;
    const float* tb = target + (size_t)b * NPTS * 3;

    float prx[4], pry[4], prz[4];      // pred (row) points, row = c*64+lane
    float tx[4], ty[4], tz[4];         // target (col) points, col = c*64+lane
    float vv[4], upc[4], Mv[4], Tv[4];
    float rxc[4], ryc[4], rzc[4];      // matched-row coords, column-attached
    int   pc[4]  = {-1, -1, -1, -1};   // matched row per column (-1 = free)
    int   way[4];
    unsigned int colu[4];              // this lane's column ids

#pragma unroll
    for (int c = 0; c < 4; ++c) {
        int idx = c * 64 + lane;
        prx[c] = pb[idx * 3 + 0]; pry[c] = pb[idx * 3 + 1]; prz[c] = pb[idx * 3 + 2];
        tx[c]  = tb[idx * 3 + 0]; ty[c]  = tb[idx * 3 + 1]; tz[c]  = tb[idx * 3 + 2];
        upc[c] = 0.f; rxc[c] = 0.f; ryc[c] = 0.f; rzc[c] = 0.f; Tv[c] = 0.f;
        colu[c] = (unsigned int)idx;
    }

    // ---- Phase 1a: column reduction. vv[c] = min_r d(r, col), colrow = argmin ----
    float colmin[4] = {BIGF, BIGF, BIGF, BIGF};
    int   colrow[4] = {0, 0, 0, 0};
#pragma unroll
    for (int rs = 0; rs < 4; ++rs) {
        for (int rl = 0; rl < 64; ++rl) {
            float bx = rlane(prx[rs], rl), by = rlane(pry[rs], rl), bz = rlane(prz[rs], rl);
            int r = rs * 64 + rl;
#pragma unroll
            for (int c = 0; c < 4; ++c) {
                float dx = bx - tx[c], dy = by - ty[c], dz = bz - tz[c];
                float d = rawsqrt(dx * dx + dy * dy + dz * dz);
                if (d < colmin[c]) { colmin[c] = d; colrow[c] = r; }
            }
        }
    }
#pragma unroll
    for (int c = 0; c < 4; ++c) vv[c] = colmin[c];

    // ---- Phase 1b: greedy claim — column (ascending) claims its argmin row if free ----
    unsigned long long frm[4];         // free-row masks (wave-uniform values)
    frm[0] = frm[1] = frm[2] = frm[3] = ~0ull;
#pragma unroll
    for (int cs = 0; cs < 4; ++cs) {
        for (int l = 0; l < 64; ++l) {
            int r = rlanei(colrow[cs], l);
            int rs = r >> 6, rl2 = r & 63;
            unsigned long long bit = 1ull << rl2;
            bool free_row = (SEL4(frm, rs) & bit) != 0ull;
            if (free_row) {
#pragma unroll
                for (int s = 0; s < 4; ++s)
                    if (s == rs) frm[s] &= ~bit;
                float bx, by, bz;
                switch (rs) {
                    case 0:  bx = rlane(prx[0], rl2); by = rlane(pry[0], rl2); bz = rlane(prz[0], rl2); break;
                    case 1:  bx = rlane(prx[1], rl2); by = rlane(pry[1], rl2); bz = rlane(prz[1], rl2); break;
                    case 2:  bx = rlane(prx[2], rl2); by = rlane(pry[2], rl2); bz = rlane(prz[2], rl2); break;
                    default: bx = rlane(prx[3], rl2); by = rlane(pry[3], rl2); bz = rlane(prz[3], rl2); break;
                }
                if (lane == l) {
                    pc[cs] = r; upc[cs] = 0.f;
                    rxc[cs] = bx; ryc[cs] = by; rzc[cs] = bz;
                }
            }
        }
    }

    // ---- Phase 2: Dijkstra shortest-path for remaining free rows ----
    float D = 0.f;
#pragma unroll
    for (int is = 0; is < 4; ++is) {
        unsigned long long m = frm[is];
        while (m) {
            const int il = (int)__builtin_ctzll(m);
            m &= (m - 1);
            const int i = is * 64 + il;

            float rootx, rooty, rootz;
            switch (is) {
                case 0:  rootx = rlane(prx[0], il); rooty = rlane(pry[0], il); rootz = rlane(prz[0], il); break;
                case 1:  rootx = rlane(prx[1], il); rooty = rlane(pry[1], il); rootz = rlane(prz[1], il); break;
                case 2:  rootx = rlane(prx[2], il); rooty = rlane(pry[2], il); rootz = rlane(prz[2], il); break;
                default: rootx = rlane(prx[3], il); rooty = rlane(pry[3], il); rootz = rlane(prz[3], il); break;
            }

#pragma unroll
            for (int c = 0; c < 4; ++c) Mv[c] = BIGF;
            int usedm = 0;

            float bx = rootx, by = rooty, bz = rootz;
            float ukey = 0.f;          // u[i0] - D_at_entry
            int j0 = -1;
            int jfin = 0;
            bool have_spare = false;
            unsigned int spare_key = 0xFFFFFFFFu;

            while (true) {
                float t[4];
#pragma unroll
                for (int c = 0; c < 4; ++c) t[c] = vv[c] + ukey;

                unsigned int k[4];
#pragma unroll
                for (int c = 0; c < 4; ++c) {
                    float dx = bx - tx[c], dy = by - ty[c], dz = bz - tz[c];
                    float d = rawsqrt(dx * dx + dy * dy + dz * dz);
                    float cand = d - t[c];
                    const bool fr = !((usedm >> c) & 1);
                    if (fr && cand < Mv[c]) { Mv[c] = cand; way[c] = j0; }
                    k[c] = fr ? ((__float_as_uint(Mv[c]) & 0xFFFFFF00u) | colu[c])
                              : 0xFFFFFFFFu;
                }
                // local (min, 2nd-min) fold over this lane's 4 keys
                unsigned int a1 = (min)(k[0], k[1]), a2 = (max)(k[0], k[1]);
                unsigned int b1 = (min)(k[2], k[3]), b2 = (max)(k[2], k[3]);
                unsigned int lm1 = (min)(a1, b1);
                unsigned int lm2 = (min)((max)(a1, b1), (min)(a2, b2));

                unsigned int kk;
                if (have_spare && __ballot(lm1 < spare_key) == 0ull) {
                    // No free column beats the spare -> spare IS the min. Skip reduce.
                    kk = spare_key;
                    have_spare = false;
                } else {
                    const PairU p = wave_pairmin_bcast(lm1, lm2);
                    kk = p.m1;
                    spare_key = p.m2;
                    have_spare = true;
                }

                const int   j1   = (int)(kk & 0xFFu);
                const float gmin = __uint_as_float(kk & 0xFFFFFF00u);
                const int osl = j1 >> 6, oln = j1 & 63;

                int pj; float uj, nbx, nby, nbz;
                switch (osl) {
                    case 0:  pj = rlanei(pc[0], oln); uj = rlane(upc[0], oln); nbx = rlane(rxc[0], oln); nby = rlane(ryc[0], oln); nbz = rlane(rzc[0], oln); break;
                    case 1:  pj = rlanei(pc[1], oln); uj = rlane(upc[1], oln); nbx = rlane(rxc[1], oln); nby = rlane(ryc[1], oln); nbz = rlane(rzc[1], oln); break;
                    case 2:  pj = rlanei(pc[2], oln); uj = rlane(upc[2], oln); nbx = rlane(rxc[2], oln); nby = rlane(ryc[2], oln); nbz = rlane(rzc[2], oln); break;
                    default: pj = rlanei(pc[3], oln); uj = rlane(upc[3], oln); nbx = rlane(rxc[3], oln); nby = rlane(ryc[3], oln); nbz = rlane(rzc[3], oln); break;
                }
                if (pj < 0) { jfin = j1; D = gmin; break; }

                // Owner bookkeeping only (dual math deferred to commit via Tv)
#pragma unroll
                for (int c = 0; c < 4; ++c)
                    if (c == osl && lane == oln) {
                        usedm |= (1 << c);
                        Tv[c] = gmin;
                    }

                bx = nbx; by = nby; bz = nbz;
                ukey = uj - gmin;
                j0 = j1;
            }

            // Commit duals for tree columns: net amount = D_final - D_at_use
#pragma unroll
            for (int c = 0; c < 4; ++c)
                if ((usedm >> c) & 1) { vv[c] += Tv[c] - D; upc[c] += D - Tv[c]; }

            // Augment along alternating path
            int jc = jfin;
            while (true) {
                const int osl = jc >> 6, oln = jc & 63;
                int jw;
                switch (osl) {
                    case 0:  jw = rlanei(way[0], oln); break;
                    case 1:  jw = rlanei(way[1], oln); break;
                    case 2:  jw = rlanei(way[2], oln); break;
                    default: jw = rlanei(way[3], oln); break;
                }
                int np_; float nup, nrx, nry, nrz;
                if (jw < 0) {
                    np_ = i; nup = D; nrx = rootx; nry = rooty; nrz = rootz;
                } else {
                    const int wsl = jw >> 6, wln = jw & 63;
                    switch (wsl) {
                        case 0:  np_ = rlanei(pc[0], wln); nup = rlane(upc[0], wln); nrx = rlane(rxc[0], wln); nry = rlane(ryc[0], wln); nrz = rlane(rzc[0], wln); break;
                        case 1:  np_ = rlanei(pc[1], wln); nup = rlane(upc[1], wln); nrx = rlane(rxc[1], wln); nry = rlane(ryc[1], wln); nrz = rlane(rzc[1], wln); break;
                        case 2:  np_ = rlanei(pc[2], wln); nup = rlane(upc[2], wln); nrx = rlane(rxc[2], wln); nry = rlane(ryc[2], wln); nrz = rlane(rzc[2], wln); break;
                        default: np_ = rlanei(pc[3], wln); nup = rlane(upc[3], wln); nrx = rlane(rxc[3], wln); nry = rlane(ryc[3], wln); nrz = rlane(rzc[3], wln); break;
                    }
                }
#pragma unroll
                for (int c = 0; c < 4; ++c)
                    if (c == osl && lane == oln) {
                        pc[c] = np_; upc[c] = nup;
                        rxc[c] = nrx; ryc[c] = nry; rzc[c] = nrz;
                    }
                if (jw < 0) break;
                jc = jw;
            }
        }
    }

    // ---- Matched cost (coords column-attached; IEEE sqrt for final accuracy) ----
    float s = 0.f;
#pragma unroll
    for (int c = 0; c < 4; ++c) {
        float dx = rxc[c] - tx[c], dy = ryc[c] - ty[c], dz = rzc[c] - tz[c];
        s += sqrtf(dx * dx + dy * dy + dz * dz);
    }
#pragma unroll
    for (int off = 1; off < 64; off <<= 1) s += __shfl_xor(s, off, 64);
    if (lane == 0) atomicAdd(out, s / (float)NBATCH);
}

extern "C" void kernel_launch(void* const* d_in, const int* in_sizes, int n_in,
                              void* d_out, int out_size, void* d_ws, size_t ws_size,
                              hipStream_t stream) {
    const float* pred   = (const float*)d_in[0];
    const float* target = (const float*)d_in[1];
    float* out = (float*)d_out;

    zero_out_kernel<<<1, 64, 0, stream>>>(out, out_size);
    hungarian_wave<<<NBATCH, 64, 0, stream>>>(pred, target, out);
}